// Round 10
// baseline (122.039 us; speedup 1.0000x reference)
//
#include <hip/hip_runtime.h>
#include <hip/hip_bf16.h>
#include <cstdint>

#define SEQ   1024
#define DOUT  1024
#define KDIM  1024
#define MTOT  4096      // BS*SEQ

typedef __bf16 bf16x8 __attribute__((ext_vector_type(8)));
typedef float  f32x4  __attribute__((ext_vector_type(4)));

__device__ inline unsigned short f2bf(float f) {
  union { float f; unsigned u; } a; a.f = f;
  unsigned r = a.u + 0x7fff + ((a.u >> 16) & 1);   // RNE
  return (unsigned short)(r >> 16);
}

__device__ inline void gl16(const void* g, void* l) {
  __builtin_amdgcn_global_load_lds((__attribute__((address_space(1))) void*)g,
                                   (__attribute__((address_space(3))) void*)l, 16, 0, 0);
}

// Launch 1: thin GEMM + x-cvt fused. Block (bm,ks): (1) cvt x slice [64r x 256c]
// f32->bf16 coalesced into xb (global); (2) build B-panel [8 chunks][48][32] in LDS
// from f32 phi/la; (3) __syncthreads (drains vmcnt -> own xb lines L2-visible);
// (4) proven R9 K-loop: gl16 A-staging from xb + MFMA. mwzP[ks][c][row].
__global__ __launch_bounds__(256) void k_mwz(const float* __restrict__ x, unsigned short* __restrict__ xb,
                                             const float* __restrict__ phi, const float* __restrict__ la,
                                             float* __restrict__ mwzP) {
  __shared__ unsigned short As[64 * 32];      // per-K-step A stage (R9 layout)
  __shared__ unsigned short Bp[8 * 48 * 32];  // persistent B panel, 24 KB
  int bm = blockIdx.x, ks = blockIdx.y;
  int t = threadIdx.x, wave = t >> 6, lane = t & 63;
  int quad = lane >> 4, lr = lane & 15;

  // (1) coalesced cvt: 64 rows x 64 ushort4-cols
#pragma unroll
  for (int j = 0; j < 16; ++j) {
    int u = j * 256 + t;
    int row = u >> 6, c4 = u & 63;
    size_t base = (size_t)(bm * 64 + row) * KDIM + ks * 256;
    float4 v = *((const float4*)(x + base) + c4);
    ushort4 o; o.x = f2bf(v.x); o.y = f2bf(v.y); o.z = f2bf(v.z); o.w = f2bf(v.w);
    *((ushort4*)(xb + base) + c4) = o;
  }
  // (2) B panel: rows 0..7 phi^T, 8..39 A2^T, 40..47 zero; chunk layout matches R9 Bs
  for (int e = t; e < 48 * 256; e += 256) {
    int r = e >> 8, dc = e & 255, d = ks * 256 + dc;
    float v;
    if (r < 8)       v = phi[d * 8 + r];
    else if (r < 40) { int kr = r - 8; v = la[(kr >> 2) * 4096 + d * 4 + (kr & 3)]; }
    else             v = 0.f;
    Bp[(dc >> 5) * 1536 + r * 32 + (dc & 31)] = f2bf(v);
  }

  const unsigned short* aG = xb + (size_t)bm * 64 * KDIM + ks * 256;
  int r0 = t >> 2, c0 = (t & 3) * 8;
  f32x4 acc[3];
#pragma unroll
  for (int i = 0; i < 3; ++i) acc[i] = (f32x4){0.f, 0.f, 0.f, 0.f};

  for (int kb = 0; kb < 256; kb += 32) {
    __syncthreads();                          // first iter also publishes xb writes
    gl16(aG + (size_t)r0 * KDIM + kb + c0, &As[wave * 512]);
    __syncthreads();
    bf16x8 af = *(const bf16x8*)&As[(wave * 16 + lr) * 32 + quad * 8];
    const unsigned short* bc = &Bp[(kb >> 5) * 1536];
#pragma unroll
    for (int ni = 0; ni < 3; ++ni) {
      bf16x8 bfr = *(const bf16x8*)&bc[(ni * 16 + lr) * 32 + quad * 8];
      acc[ni] = __builtin_amdgcn_mfma_f32_16x16x32_bf16(af, bfr, acc[ni], 0, 0, 0);
    }
  }
#pragma unroll
  for (int ni = 0; ni < 3; ++ni) {
    int c = ni * 16 + lr;
#pragma unroll
    for (int rg = 0; rg < 4; ++rg) {
      int row = bm * 64 + wave * 16 + quad * 4 + rg;
      if (c < 40) mwzP[(size_t)(ks * 40 + c) * MTOT + row] = acc[ni][rg];
    }
  }
}

// Launch 2: blocks [0,128): scan+gate (b=blk>>5, c=blk&31), thr inline;
// [128,384): W->Wc bf16 (4096 elems/block, coalesced); [384,392): B2T.
__global__ __launch_bounds__(1024) void k_sgp(const float* __restrict__ mwzP,
                                              const int* __restrict__ inst, const int* __restrict__ pad,
                                              const float* __restrict__ W, const float* __restrict__ lb,
                                              unsigned short* __restrict__ Wc, unsigned short* __restrict__ B2T,
                                              unsigned short* __restrict__ gb) {
  int blk = blockIdx.x, tid = threadIdx.x;
  if (blk >= 128) {
    if (blk < 384) {
      size_t e4 = (size_t)(blk - 128) * 1024 + tid;   // float4 index into W (1M elems)
      float4 v = ((const float4*)W)[e4];
      ushort4 o; o.x = f2bf(v.x); o.y = f2bf(v.y); o.z = f2bf(v.z); o.w = f2bf(v.w);
      ((ushort4*)Wc)[e4] = o;
    } else {
      int i = (blk - 384) * 4096 + tid * 4;           // B2T[n][kr] = lb[kr][n]
      int n = i >> 5, kr = i & 31;
      ushort4 o;
      o.x = f2bf(lb[(kr + 0) * 1024 + n]);
      o.y = f2bf(lb[(kr + 1) * 1024 + n]);
      o.z = f2bf(lb[(kr + 2) * 1024 + n]);
      o.w = f2bf(lb[(kr + 3) * 1024 + n]);
      *(ushort4*)(B2T + i) = o;
    }
    return;
  }
  int b = blk >> 5, c = blk & 31;
  int wv = tid >> 6, lane = tid & 63;
  __shared__ float wsz[16], wsp[16];
  __shared__ float sv, spc;
  __shared__ int fos[16], nos[16], ths;
  {
    int iv = inst[b * SEQ + tid];
    int fo = iv ? tid : (1 << 30), no = iv;
#pragma unroll
    for (int d = 1; d < 64; d <<= 1) { fo = min(fo, __shfl_xor(fo, d)); no += __shfl_xor(no, d); }
    if (lane == 0) { fos[wv] = fo; nos[wv] = no; }
  }
  __syncthreads();
  if (tid == 0) {
    int F = 1 << 30, N = 0;
#pragma unroll
    for (int i = 0; i < 16; ++i) { F = min(F, fos[i]); N += nos[i]; }
    ths = (N > 0) ? F + N : 0;
  }
  int q = b * SEQ + tid;
  float pm = (float)pad[q];
  float z = 0.f;
#pragma unroll
  for (int s = 0; s < 4; ++s) z += mwzP[(size_t)(s * 40 + 8 + c) * MTOT + q];
  z *= pm;
  float vz = z, vp = pm;
#pragma unroll
  for (int d = 1; d < 64; d <<= 1) {
    float oz = __shfl_up(vz, d), op = __shfl_up(vp, d);
    if (lane >= d) { vz += oz; vp += op; }
  }
  if (lane == 63) { wsz[wv] = vz; wsp[wv] = vp; }
  __syncthreads();
  if (wv == 0 && lane < 16) {
    float oz = wsz[lane], op = wsp[lane], sz = oz, sp = op;
#pragma unroll
    for (int d = 1; d < 16; d <<= 1) {
      float tz = __shfl_up(sz, d), tp = __shfl_up(sp, d);
      if (lane >= d) { sz += tz; sp += tp; }
    }
    wsz[lane] = sz - oz; wsp[lane] = sp - op;   // exclusive wave offsets
  }
  __syncthreads();
  vz += wsz[wv]; vp += wsp[wv];
  int th = ths;
  if (th > 0 && tid == th - 1) { sv = vz; spc = vp; }
  __syncthreads();
  unsigned short o = 0;
  if (pm != 0.f) {
    bool own = (tid + 1 >= th);
    float Tv  = own ? vz : sv;
    float cnt = own ? vp : spc;
    float C[8], mx = -1e30f;
#pragma unroll
    for (int k = 0; k < 8; ++k) {
      float m = 0.f;
#pragma unroll
      for (int s = 0; s < 4; ++s) m += mwzP[(size_t)(s * 40 + k) * MTOT + q];
      C[k] = m; mx = fmaxf(mx, m);
    }
    float sm = 0.f;
#pragma unroll
    for (int k = 0; k < 8; ++k) { C[k] = __expf(C[k] - mx); sm += C[k]; }
    o = f2bf(C[c >> 2] * Tv / (sm * cnt));
  }
  gb[(size_t)q * 32 + c] = o;
}

// Launch 3: BM=128 x BN=64 GEMM, 512 blocks (2/CU), single-buffer 2-barrier K-loop
// with register-only adapter prologue (R9-proven). out = x@W^T + bias + g@B2.
__global__ __launch_bounds__(256) void k_gemm(const unsigned short* __restrict__ A,
                                              const unsigned short* __restrict__ Wc,
                                              const unsigned short* __restrict__ gb,
                                              const unsigned short* __restrict__ B2T,
                                              float* __restrict__ out,
                                              const float* __restrict__ bias) {
  __shared__ unsigned short As[128 * 32];  // 8 KB
  __shared__ unsigned short Bs[64 * 32];   // 4 KB
  int bm = blockIdx.x, bn = blockIdx.y;
  int t = threadIdx.x;
  int wave = t >> 6, lane = t & 63;
  int wr = wave >> 1, wc = wave & 1;       // wave: 64 rows x 32 cols
  int quad = lane >> 4, lr = lane & 15;
  f32x4 acc[4][2];
#pragma unroll
  for (int i = 0; i < 4; i++)
#pragma unroll
    for (int j = 0; j < 2; j++) acc[i][j] = (f32x4){0.f, 0.f, 0.f, 0.f};

  // adapter prologue: acc += g-tile @ B2 (register fragments only)
  {
    bf16x8 ga[4], gBf[2];
#pragma unroll
    for (int mi = 0; mi < 4; mi++)
      ga[mi] = *(const bf16x8*)(gb + (size_t)(bm * 128 + wr * 64 + mi * 16 + lr) * 32 + quad * 8);
#pragma unroll
    for (int ni = 0; ni < 2; ni++)
      gBf[ni] = *(const bf16x8*)(B2T + (size_t)(bn * 64 + wc * 32 + ni * 16 + lr) * 32 + quad * 8);
#pragma unroll
    for (int mi = 0; mi < 4; mi++)
#pragma unroll
      for (int ni = 0; ni < 2; ni++)
        acc[mi][ni] = __builtin_amdgcn_mfma_f32_16x16x32_bf16(ga[mi], gBf[ni], acc[mi][ni], 0, 0, 0);
  }

  const unsigned short* aG = A + (size_t)bm * 128 * KDIM;
  const unsigned short* bG = Wc + (size_t)bn * 64 * KDIM;
  int r0 = t >> 2, c0 = (t & 3) * 8;

  for (int kb = 0; kb < KDIM; kb += 32) {
    __syncthreads();
    gl16(aG + (size_t)r0 * KDIM + kb + c0,        &As[wave * 512]);
    gl16(aG + (size_t)(r0 + 64) * KDIM + kb + c0, &As[2048 + wave * 512]);
    gl16(bG + (size_t)r0 * KDIM + kb + c0,        &Bs[wave * 512]);
    __syncthreads();
    bf16x8 af[4], bfr[2];
#pragma unroll
    for (int mi = 0; mi < 4; mi++) af[mi]  = *(const bf16x8*)&As[(wr * 64 + mi * 16 + lr) * 32 + quad * 8];
#pragma unroll
    for (int ni = 0; ni < 2; ni++) bfr[ni] = *(const bf16x8*)&Bs[(wc * 32 + ni * 16 + lr) * 32 + quad * 8];
#pragma unroll
    for (int mi = 0; mi < 4; mi++)
#pragma unroll
      for (int ni = 0; ni < 2; ni++)
        acc[mi][ni] = __builtin_amdgcn_mfma_f32_16x16x32_bf16(af[mi], bfr[ni], acc[mi][ni], 0, 0, 0);
  }

  // epilogue: C/D layout col=lane&15, row=quad*4+reg
#pragma unroll
  for (int mi = 0; mi < 4; mi++) {
#pragma unroll
    for (int ni = 0; ni < 2; ni++) {
      int col = bn * 64 + wc * 32 + ni * 16 + lr;
      float bv = bias[col];
#pragma unroll
      for (int rg = 0; rg < 4; ++rg) {
        int row = bm * 128 + wr * 64 + mi * 16 + quad * 4 + rg;
        out[(size_t)row * DOUT + col] = acc[mi][ni][rg] + bv;
      }
    }
  }
}

extern "C" void kernel_launch(void* const* d_in, const int* in_sizes, int n_in,
                              void* d_out, int out_size, void* d_ws, size_t ws_size,
                              hipStream_t stream) {
  const float* x    = (const float*)d_in[0];
  const float* phi  = (const float*)d_in[1];
  const float* la   = (const float*)d_in[2];
  const float* lb   = (const float*)d_in[3];
  const float* W    = (const float*)d_in[4];
  const float* bias = (const float*)d_in[5];
  const int*   inst = (const int*)d_in[6];
  const int*   pad  = (const int*)d_in[7];
  float* out = (float*)d_out;

  char* ws = (char*)d_ws;
  unsigned short* xb  = (unsigned short*)ws;                   // 8388608 B
  unsigned short* Wc  = (unsigned short*)(ws + 8388608);       // [1024][1024] bf16 = 2097152 B
  unsigned short* B2T = (unsigned short*)(ws + 10485760);      // [1024][32] bf16 = 65536 B
  float* mwzP = (float*)(ws + 10551296);                       // [4][40][4096] f32 = 2621440 B
  unsigned short* gb  = (unsigned short*)(ws + 13172736);      // [4096][32] bf16 = 262144 B

  hipLaunchKernelGGL(k_mwz,  dim3(64, 4),  dim3(256),  0, stream, x, xb, phi, la, mwzP);
  hipLaunchKernelGGL(k_sgp,  dim3(392),    dim3(1024), 0, stream, mwzP, inst, pad, W, lb, Wc, B2T, gb);
  hipLaunchKernelGGL(k_gemm, dim3(32, 16), dim3(256),  0, stream, xb, Wc, gb, B2T, out, bias);
}

// Round 11
// 115.071 us; speedup vs baseline: 1.0606x; 1.0606x over previous
//
#include <hip/hip_runtime.h>
#include <hip/hip_bf16.h>
#include <cstdint>

#define SEQ   1024
#define DOUT  1024
#define KDIM  1024
#define MTOT  4096      // BS*SEQ
#define WCROWS 1072     // 1024 W + 8 phi + 32 A2 + 8 zero

typedef __bf16 bf16x8 __attribute__((ext_vector_type(8)));
typedef float  f32x4  __attribute__((ext_vector_type(4)));

__device__ inline unsigned short f2bf(float f) {
  union { float f; unsigned u; } a; a.f = f;
  unsigned r = a.u + 0x7fff + ((a.u >> 16) & 1);   // RNE
  return (unsigned short)(r >> 16);
}

__device__ inline void gl16(const void* g, void* l) {
  __builtin_amdgcn_global_load_lds((__attribute__((address_space(1))) void*)g,
                                   (__attribute__((address_space(3))) void*)l, 16, 0, 0);
}

// fused prologue: [0,4096) cvt x; [4096,8384) build Wc; [8384,8512) B2T; 8512 thr
__global__ __launch_bounds__(256) void k_prep(const float4* __restrict__ x, ushort4* __restrict__ xb,
                                              const float* __restrict__ W, const float* __restrict__ phi,
                                              const float* __restrict__ la, const float* __restrict__ lb,
                                              unsigned short* __restrict__ Wc, unsigned short* __restrict__ B2T,
                                              const int* __restrict__ inst, int* __restrict__ thr) {
  int blk = blockIdx.x, tid = threadIdx.x;
  if (blk < 4096) {
    int i = blk * 256 + tid;
    float4 v = x[i];
    ushort4 o; o.x = f2bf(v.x); o.y = f2bf(v.y); o.z = f2bf(v.z); o.w = f2bf(v.w);
    xb[i] = o;
  } else if (blk < 8384) {
    int i = (blk - 4096) * 256 + tid;            // WCROWS*1024 exact
    int row = i >> 10, d = i & 1023;
    float v;
    if (row < 1024)       v = W[i];
    else if (row < 1032)  v = phi[d * 8 + (row - 1024)];
    else if (row < 1064)  { int kr = row - 1032; v = la[(kr >> 2) * 4096 + d * 4 + (kr & 3)]; }
    else                  v = 0.f;
    Wc[i] = f2bf(v);
  } else if (blk < 8512) {
    int i = (blk - 8384) * 256 + tid;            // 32768 exact: B2T[n][kr] = lb[kr][n]
    int n = i >> 5, kr = i & 31;
    B2T[i] = f2bf(lb[kr * 1024 + n]);
  } else {
    int b = tid >> 6, lane = tid & 63;           // wave b handles batch b
    int fo = 1 << 30, no = 0;
#pragma unroll
    for (int j = 0; j < 16; ++j) {
      int p = j * 64 + lane;
      int iv = inst[b * SEQ + p];
      if (iv > 0) fo = min(fo, p);
      no += iv;
    }
#pragma unroll
    for (int d = 1; d < 64; d <<= 1) { fo = min(fo, __shfl_xor(fo, d)); no += __shfl_xor(no, d); }
    if (lane == 0) thr[b] = (no > 0) ? fo + no : 0;
  }
}

// thin GEMM, 4-way K-split (single-buffered — dbuf measured slower, R6):
// mwzP[ks][c][row] = (x @ [phi|A2])[row][c] over K-quarter ks
__global__ __launch_bounds__(256) void k_mwz(const unsigned short* __restrict__ xb,
                                             const unsigned short* __restrict__ Wc,
                                             float* __restrict__ mwzP) {
  __shared__ unsigned short As[64 * 32];
  __shared__ unsigned short Bs[48 * 32];
  int bm = blockIdx.x, ks = blockIdx.y;
  int t = threadIdx.x, wave = t >> 6, lane = t & 63;
  int quad = lane >> 4, lr = lane & 15;
  f32x4 acc[3];
#pragma unroll
  for (int i = 0; i < 3; ++i) acc[i] = (f32x4){0.f, 0.f, 0.f, 0.f};
  const unsigned short* aG = xb + (size_t)bm * 64 * KDIM + ks * 256;
  const unsigned short* bG = Wc + (size_t)1024 * KDIM + ks * 256;
  int r0 = t >> 2, c0 = (t & 3) * 8;
  for (int kb = 0; kb < 256; kb += 32) {
    __syncthreads();
    gl16(aG + (size_t)r0 * KDIM + kb + c0, &As[wave * 512]);
    if (t < 192) gl16(bG + (size_t)r0 * KDIM + kb + c0, &Bs[wave * 512]);
    __syncthreads();
    bf16x8 af = *(const bf16x8*)&As[(wave * 16 + lr) * 32 + quad * 8];
#pragma unroll
    for (int ni = 0; ni < 3; ++ni) {
      bf16x8 bfr = *(const bf16x8*)&Bs[(ni * 16 + lr) * 32 + quad * 8];
      acc[ni] = __builtin_amdgcn_mfma_f32_16x16x32_bf16(af, bfr, acc[ni], 0, 0, 0);
    }
  }
#pragma unroll
  for (int ni = 0; ni < 3; ++ni) {
    int c = ni * 16 + lr;
#pragma unroll
    for (int rg = 0; rg < 4; ++rg) {
      int row = bm * 64 + wave * 16 + quad * 4 + rg;
      if (c < 40) mwzP[(size_t)(ks * 40 + c) * MTOT + row] = acc[ni][rg];
    }
  }
}

// fused scan+gate: block (b,c): scan z_c*pad and pad over s, then
// gb[q][c] = softmax_k(mw)[c/4] * Tv / cnt   (e = max(thr,s+1)-1: own pos if
// s+1>=thr, else the single shared position thr-1)
__global__ __launch_bounds__(1024) void k_scan_gate(const float* __restrict__ mwzP,
                                                    const int* __restrict__ pad, const int* __restrict__ thr,
                                                    unsigned short* __restrict__ gb) {
  int b = blockIdx.x, c = blockIdx.y;
  int tid = threadIdx.x, wv = tid >> 6, lane = tid & 63;
  __shared__ float wsz[16], wsp[16];
  __shared__ float sv, spc;
  int q = b * SEQ + tid;
  float pm = (float)pad[q];
  float z = 0.f;
#pragma unroll
  for (int s = 0; s < 4; ++s) z += mwzP[(size_t)(s * 40 + 8 + c) * MTOT + q];
  z *= pm;
  float vz = z, vp = pm;
#pragma unroll
  for (int d = 1; d < 64; d <<= 1) {
    float oz = __shfl_up(vz, d), op = __shfl_up(vp, d);
    if (lane >= d) { vz += oz; vp += op; }
  }
  if (lane == 63) { wsz[wv] = vz; wsp[wv] = vp; }
  __syncthreads();
  if (wv == 0 && lane < 16) {
    float oz = wsz[lane], op = wsp[lane], sz = oz, sp = op;
#pragma unroll
    for (int d = 1; d < 16; d <<= 1) {
      float tz = __shfl_up(sz, d), tp = __shfl_up(sp, d);
      if (lane >= d) { sz += tz; sp += tp; }
    }
    wsz[lane] = sz - oz; wsp[lane] = sp - op;   // exclusive wave offsets
  }
  __syncthreads();
  vz += wsz[wv]; vp += wsp[wv];
  int th = thr[b];
  if (th > 0 && tid == th - 1) { sv = vz; spc = vp; }
  __syncthreads();
  unsigned short o = 0;
  if (pm != 0.f) {
    bool own = (tid + 1 >= th);
    float Tv  = own ? vz : sv;
    float cnt = own ? vp : spc;
    float C[8], mx = -1e30f;
#pragma unroll
    for (int k = 0; k < 8; ++k) {
      float m = 0.f;
#pragma unroll
      for (int s = 0; s < 4; ++s) m += mwzP[(size_t)(s * 40 + k) * MTOT + q];
      C[k] = m; mx = fmaxf(mx, m);
    }
    float sm = 0.f;
#pragma unroll
    for (int k = 0; k < 8; ++k) { C[k] = __expf(C[k] - mx); sm += C[k]; }
    o = f2bf(C[c >> 2] * Tv / (sm * cnt));
  }
  gb[(size_t)q * 32 + c] = o;
}

// BM=128 x BN=64 GEMM, 512 blocks (2/CU), single-buffer 2-barrier K-loop (proven R5).
// Adapter done FIRST as a register-only prologue: A-frag = 16 contiguous bytes of gb,
// B-frag = 16 contiguous bytes of B2T — no LDS, no barriers, no branch in main loop.
__global__ __launch_bounds__(256) void k_gemm(const unsigned short* __restrict__ A,
                                              const unsigned short* __restrict__ Wc,
                                              const unsigned short* __restrict__ gb,
                                              const unsigned short* __restrict__ B2T,
                                              float* __restrict__ out,
                                              const float* __restrict__ bias) {
  __shared__ unsigned short As[128 * 32];  // 8 KB
  __shared__ unsigned short Bs[64 * 32];   // 4 KB
  int bm = blockIdx.x, bn = blockIdx.y;
  int t = threadIdx.x;
  int wave = t >> 6, lane = t & 63;
  int wr = wave >> 1, wc = wave & 1;       // wave: 64 rows x 32 cols
  int quad = lane >> 4, lr = lane & 15;
  f32x4 acc[4][2];
#pragma unroll
  for (int i = 0; i < 4; i++)
#pragma unroll
    for (int j = 0; j < 2; j++) acc[i][j] = (f32x4){0.f, 0.f, 0.f, 0.f};

  // ---- adapter prologue: acc += g-tile @ B2 (register fragments only) ----
  {
    bf16x8 ga[4], gBf[2];
#pragma unroll
    for (int mi = 0; mi < 4; mi++)
      ga[mi] = *(const bf16x8*)(gb + (size_t)(bm * 128 + wr * 64 + mi * 16 + lr) * 32 + quad * 8);
#pragma unroll
    for (int ni = 0; ni < 2; ni++)
      gBf[ni] = *(const bf16x8*)(B2T + (size_t)(bn * 64 + wc * 32 + ni * 16 + lr) * 32 + quad * 8);
#pragma unroll
    for (int mi = 0; mi < 4; mi++)
#pragma unroll
      for (int ni = 0; ni < 2; ni++)
        acc[mi][ni] = __builtin_amdgcn_mfma_f32_16x16x32_bf16(ga[mi], gBf[ni], acc[mi][ni], 0, 0, 0);
  }

  const unsigned short* aG = A + (size_t)bm * 128 * KDIM;
  const unsigned short* bG = Wc + (size_t)bn * 64 * KDIM;
  int r0 = t >> 2, c0 = (t & 3) * 8;

  for (int kb = 0; kb < KDIM; kb += 32) {
    __syncthreads();
    gl16(aG + (size_t)r0 * KDIM + kb + c0,        &As[wave * 512]);
    gl16(aG + (size_t)(r0 + 64) * KDIM + kb + c0, &As[2048 + wave * 512]);
    gl16(bG + (size_t)r0 * KDIM + kb + c0,        &Bs[wave * 512]);
    __syncthreads();
    bf16x8 af[4], bfr[2];
#pragma unroll
    for (int mi = 0; mi < 4; mi++) af[mi]  = *(const bf16x8*)&As[(wr * 64 + mi * 16 + lr) * 32 + quad * 8];
#pragma unroll
    for (int ni = 0; ni < 2; ni++) bfr[ni] = *(const bf16x8*)&Bs[(wc * 32 + ni * 16 + lr) * 32 + quad * 8];
#pragma unroll
    for (int mi = 0; mi < 4; mi++)
#pragma unroll
      for (int ni = 0; ni < 2; ni++)
        acc[mi][ni] = __builtin_amdgcn_mfma_f32_16x16x32_bf16(af[mi], bfr[ni], acc[mi][ni], 0, 0, 0);
  }

  // epilogue: C/D layout col=lane&15, row=quad*4+reg
#pragma unroll
  for (int mi = 0; mi < 4; mi++) {
#pragma unroll
    for (int ni = 0; ni < 2; ni++) {
      int col = bn * 64 + wc * 32 + ni * 16 + lr;
      float bv = bias[col];
#pragma unroll
      for (int rg = 0; rg < 4; ++rg) {
        int row = bm * 128 + wr * 64 + mi * 16 + quad * 4 + rg;
        out[(size_t)row * DOUT + col] = acc[mi][ni][rg] + bv;
      }
    }
  }
}

extern "C" void kernel_launch(void* const* d_in, const int* in_sizes, int n_in,
                              void* d_out, int out_size, void* d_ws, size_t ws_size,
                              hipStream_t stream) {
  const float* x    = (const float*)d_in[0];
  const float* phi  = (const float*)d_in[1];
  const float* la   = (const float*)d_in[2];
  const float* lb   = (const float*)d_in[3];
  const float* W    = (const float*)d_in[4];
  const float* bias = (const float*)d_in[5];
  const int*   inst = (const int*)d_in[6];
  const int*   pad  = (const int*)d_in[7];
  float* out = (float*)d_out;

  char* ws = (char*)d_ws;
  unsigned short* xb  = (unsigned short*)ws;                   // 8388608 B
  unsigned short* Wc  = (unsigned short*)(ws + 8388608);       // 1072*1024*2 = 2195456 B
  unsigned short* B2T = (unsigned short*)(ws + 10584064);      // [1024][32] bf16 = 65536 B
  float* mwzP = (float*)(ws + 10649600);                       // [4][40][4096] f32 = 2621440 B
  unsigned short* gb  = (unsigned short*)(ws + 13271040);      // [4096][32] bf16 = 262144 B
  int*   thr  = (int*)(ws + 13533184);                         // 16 B

  hipLaunchKernelGGL(k_prep,      dim3(8513),   dim3(256),  0, stream,
                     (const float4*)x, (ushort4*)xb, W, phi, la, lb, Wc, B2T, inst, thr);
  hipLaunchKernelGGL(k_mwz,       dim3(64, 4),  dim3(256),  0, stream, xb, Wc, mwzP);
  hipLaunchKernelGGL(k_scan_gate, dim3(4, 32),  dim3(1024), 0, stream, mwzP, pad, thr, gb);
  hipLaunchKernelGGL(k_gemm,      dim3(32, 16), dim3(256),  0, stream, xb, Wc, gb, B2T, out, bias);
}

// Round 12
// 114.273 us; speedup vs baseline: 1.0680x; 1.0070x over previous
//
#include <hip/hip_runtime.h>
#include <hip/hip_bf16.h>
#include <cstdint>

#define SEQ   1024
#define DOUT  1024
#define KDIM  1024
#define MTOT  4096      // BS*SEQ

typedef __bf16 bf16x8 __attribute__((ext_vector_type(8)));
typedef float  f32x4  __attribute__((ext_vector_type(4)));

__device__ inline unsigned short f2bf(float f) {
  union { float f; unsigned u; } a; a.f = f;
  unsigned r = a.u + 0x7fff + ((a.u >> 16) & 1);   // RNE
  return (unsigned short)(r >> 16);
}

__device__ inline void gl16(const void* g, void* l) {
  __builtin_amdgcn_global_load_lds((__attribute__((address_space(1))) void*)g,
                                   (__attribute__((address_space(3))) void*)l, 16, 0, 0);
}

// Launch 1: only what k_mwz consumes — [0,4096) x->bf16; [4096,4288) Wc rows
// 1024..1072 (phi^T, A2^T, zero pad).
__global__ __launch_bounds__(256) void k_prep(const float4* __restrict__ x, ushort4* __restrict__ xb,
                                              const float* __restrict__ phi, const float* __restrict__ la,
                                              unsigned short* __restrict__ Wc) {
  int blk = blockIdx.x, tid = threadIdx.x;
  if (blk < 4096) {
    int i = blk * 256 + tid;
    float4 v = x[i];
    ushort4 o; o.x = f2bf(v.x); o.y = f2bf(v.y); o.z = f2bf(v.z); o.w = f2bf(v.w);
    xb[i] = o;
  } else {
    int i = (blk - 4096) * 256 + tid;            // 48 rows x 1024 exact
    int row = 1024 + (i >> 10), d = i & 1023;
    float v;
    if (row < 1032)       v = phi[d * 8 + (row - 1024)];
    else if (row < 1064)  { int kr = row - 1032; v = la[(kr >> 2) * 4096 + d * 4 + (kr & 3)]; }
    else                  v = 0.f;
    Wc[(size_t)row * 1024 + d] = f2bf(v);
  }
}

// Launch 2: blocks [0,256) = thin GEMM (proven R11 k_mwz, bm=blk&63, ks=blk>>6);
// [256,4352) W->Wc bf16; [4352,4480) B2T; 4480 = thr. The memory blocks fill the
// CUs' idle wave slots while the 1-block/CU latency-bound GEMM runs.
__global__ __launch_bounds__(256) void k_mwz(const unsigned short* __restrict__ xb,
                                             const unsigned short* __restrict__ Wc0,
                                             const float* __restrict__ W, const float* __restrict__ lb,
                                             const int* __restrict__ inst,
                                             unsigned short* __restrict__ Wc, unsigned short* __restrict__ B2T,
                                             int* __restrict__ thr, float* __restrict__ mwzP) {
  __shared__ unsigned short As[64 * 32];
  __shared__ unsigned short Bs[48 * 32];
  int blk = blockIdx.x, t = threadIdx.x;
  if (blk >= 256) {
    if (blk < 4352) {
      size_t i = (size_t)(blk - 256) * 256 + t;   // 1M elems of W
      Wc[i] = f2bf(W[i]);
    } else if (blk < 4480) {
      int i = (blk - 4352) * 256 + t;             // 32768: B2T[n][kr] = lb[kr][n]
      int n = i >> 5, kr = i & 31;
      B2T[i] = f2bf(lb[kr * 1024 + n]);
    } else {
      int b = t >> 6, lane = t & 63;              // wave b handles batch b
      int fo = 1 << 30, no = 0;
#pragma unroll
      for (int j = 0; j < 16; ++j) {
        int p = j * 64 + lane;
        int iv = inst[b * SEQ + p];
        if (iv > 0) fo = min(fo, p);
        no += iv;
      }
#pragma unroll
      for (int d = 1; d < 64; d <<= 1) { fo = min(fo, __shfl_xor(fo, d)); no += __shfl_xor(no, d); }
      if (lane == 0) thr[b] = (no > 0) ? fo + no : 0;
    }
    return;
  }
  int bm = blk & 63, ks = blk >> 6;
  int wave = t >> 6, lane = t & 63;
  int quad = lane >> 4, lr = lane & 15;
  f32x4 acc[3];
#pragma unroll
  for (int i = 0; i < 3; ++i) acc[i] = (f32x4){0.f, 0.f, 0.f, 0.f};
  const unsigned short* aG = xb + (size_t)bm * 64 * KDIM + ks * 256;
  const unsigned short* bG = Wc0 + (size_t)1024 * KDIM + ks * 256;
  int r0 = t >> 2, c0 = (t & 3) * 8;
  for (int kb = 0; kb < 256; kb += 32) {
    __syncthreads();
    gl16(aG + (size_t)r0 * KDIM + kb + c0, &As[wave * 512]);
    if (t < 192) gl16(bG + (size_t)r0 * KDIM + kb + c0, &Bs[wave * 512]);
    __syncthreads();
    bf16x8 af = *(const bf16x8*)&As[(wave * 16 + lr) * 32 + quad * 8];
#pragma unroll
    for (int ni = 0; ni < 3; ++ni) {
      bf16x8 bfr = *(const bf16x8*)&Bs[(ni * 16 + lr) * 32 + quad * 8];
      acc[ni] = __builtin_amdgcn_mfma_f32_16x16x32_bf16(af, bfr, acc[ni], 0, 0, 0);
    }
  }
#pragma unroll
  for (int ni = 0; ni < 3; ++ni) {
    int c = ni * 16 + lr;
#pragma unroll
    for (int rg = 0; rg < 4; ++rg) {
      int row = bm * 64 + wave * 16 + quad * 4 + rg;
      if (c < 40) mwzP[(size_t)(ks * 40 + c) * MTOT + row] = acc[ni][rg];
    }
  }
}

// Launch 3 (unchanged R11): fused scan+gate, block (b,c)
__global__ __launch_bounds__(1024) void k_scan_gate(const float* __restrict__ mwzP,
                                                    const int* __restrict__ pad, const int* __restrict__ thr,
                                                    unsigned short* __restrict__ gb) {
  int b = blockIdx.x, c = blockIdx.y;
  int tid = threadIdx.x, wv = tid >> 6, lane = tid & 63;
  __shared__ float wsz[16], wsp[16];
  __shared__ float sv, spc;
  int q = b * SEQ + tid;
  float pm = (float)pad[q];
  float z = 0.f;
#pragma unroll
  for (int s = 0; s < 4; ++s) z += mwzP[(size_t)(s * 40 + 8 + c) * MTOT + q];
  z *= pm;
  float vz = z, vp = pm;
#pragma unroll
  for (int d = 1; d < 64; d <<= 1) {
    float oz = __shfl_up(vz, d), op = __shfl_up(vp, d);
    if (lane >= d) { vz += oz; vp += op; }
  }
  if (lane == 63) { wsz[wv] = vz; wsp[wv] = vp; }
  __syncthreads();
  if (wv == 0 && lane < 16) {
    float oz = wsz[lane], op = wsp[lane], sz = oz, sp = op;
#pragma unroll
    for (int d = 1; d < 16; d <<= 1) {
      float tz = __shfl_up(sz, d), tp = __shfl_up(sp, d);
      if (lane >= d) { sz += tz; sp += tp; }
    }
    wsz[lane] = sz - oz; wsp[lane] = sp - op;   // exclusive wave offsets
  }
  __syncthreads();
  vz += wsz[wv]; vp += wsp[wv];
  int th = thr[b];
  if (th > 0 && tid == th - 1) { sv = vz; spc = vp; }
  __syncthreads();
  unsigned short o = 0;
  if (pm != 0.f) {
    bool own = (tid + 1 >= th);
    float Tv  = own ? vz : sv;
    float cnt = own ? vp : spc;
    float C[8], mx = -1e30f;
#pragma unroll
    for (int k = 0; k < 8; ++k) {
      float m = 0.f;
#pragma unroll
      for (int s = 0; s < 4; ++s) m += mwzP[(size_t)(s * 40 + k) * MTOT + q];
      C[k] = m; mx = fmaxf(mx, m);
    }
    float sm = 0.f;
#pragma unroll
    for (int k = 0; k < 8; ++k) { C[k] = __expf(C[k] - mx); sm += C[k]; }
    o = f2bf(C[c >> 2] * Tv / (sm * cnt));
  }
  gb[(size_t)q * 32 + c] = o;
}

// Launch 4 (unchanged R11): BM=128 x BN=64 GEMM, 512 blocks (2/CU), single-buffer
// 2-barrier K-loop + register-only adapter prologue. out = x@W^T + bias + g@B2.
__global__ __launch_bounds__(256) void k_gemm(const unsigned short* __restrict__ A,
                                              const unsigned short* __restrict__ Wc,
                                              const unsigned short* __restrict__ gb,
                                              const unsigned short* __restrict__ B2T,
                                              float* __restrict__ out,
                                              const float* __restrict__ bias) {
  __shared__ unsigned short As[128 * 32];  // 8 KB
  __shared__ unsigned short Bs[64 * 32];   // 4 KB
  int bm = blockIdx.x, bn = blockIdx.y;
  int t = threadIdx.x;
  int wave = t >> 6, lane = t & 63;
  int wr = wave >> 1, wc = wave & 1;       // wave: 64 rows x 32 cols
  int quad = lane >> 4, lr = lane & 15;
  f32x4 acc[4][2];
#pragma unroll
  for (int i = 0; i < 4; i++)
#pragma unroll
    for (int j = 0; j < 2; j++) acc[i][j] = (f32x4){0.f, 0.f, 0.f, 0.f};

  // adapter prologue: acc += g-tile @ B2 (register fragments only)
  {
    bf16x8 ga[4], gBf[2];
#pragma unroll
    for (int mi = 0; mi < 4; mi++)
      ga[mi] = *(const bf16x8*)(gb + (size_t)(bm * 128 + wr * 64 + mi * 16 + lr) * 32 + quad * 8);
#pragma unroll
    for (int ni = 0; ni < 2; ni++)
      gBf[ni] = *(const bf16x8*)(B2T + (size_t)(bn * 64 + wc * 32 + ni * 16 + lr) * 32 + quad * 8);
#pragma unroll
    for (int mi = 0; mi < 4; mi++)
#pragma unroll
      for (int ni = 0; ni < 2; ni++)
        acc[mi][ni] = __builtin_amdgcn_mfma_f32_16x16x32_bf16(ga[mi], gBf[ni], acc[mi][ni], 0, 0, 0);
  }

  const unsigned short* aG = A + (size_t)bm * 128 * KDIM;
  const unsigned short* bG = Wc + (size_t)bn * 64 * KDIM;
  int r0 = t >> 2, c0 = (t & 3) * 8;

  for (int kb = 0; kb < KDIM; kb += 32) {
    __syncthreads();
    gl16(aG + (size_t)r0 * KDIM + kb + c0,        &As[wave * 512]);
    gl16(aG + (size_t)(r0 + 64) * KDIM + kb + c0, &As[2048 + wave * 512]);
    gl16(bG + (size_t)r0 * KDIM + kb + c0,        &Bs[wave * 512]);
    __syncthreads();
    bf16x8 af[4], bfr[2];
#pragma unroll
    for (int mi = 0; mi < 4; mi++) af[mi]  = *(const bf16x8*)&As[(wr * 64 + mi * 16 + lr) * 32 + quad * 8];
#pragma unroll
    for (int ni = 0; ni < 2; ni++) bfr[ni] = *(const bf16x8*)&Bs[(wc * 32 + ni * 16 + lr) * 32 + quad * 8];
#pragma unroll
    for (int mi = 0; mi < 4; mi++)
#pragma unroll
      for (int ni = 0; ni < 2; ni++)
        acc[mi][ni] = __builtin_amdgcn_mfma_f32_16x16x32_bf16(af[mi], bfr[ni], acc[mi][ni], 0, 0, 0);
  }

  // epilogue: C/D layout col=lane&15, row=quad*4+reg
#pragma unroll
  for (int mi = 0; mi < 4; mi++) {
#pragma unroll
    for (int ni = 0; ni < 2; ni++) {
      int col = bn * 64 + wc * 32 + ni * 16 + lr;
      float bv = bias[col];
#pragma unroll
      for (int rg = 0; rg < 4; ++rg) {
        int row = bm * 128 + wr * 64 + mi * 16 + quad * 4 + rg;
        out[(size_t)row * DOUT + col] = acc[mi][ni][rg] + bv;
      }
    }
  }
}

extern "C" void kernel_launch(void* const* d_in, const int* in_sizes, int n_in,
                              void* d_out, int out_size, void* d_ws, size_t ws_size,
                              hipStream_t stream) {
  const float* x    = (const float*)d_in[0];
  const float* phi  = (const float*)d_in[1];
  const float* la   = (const float*)d_in[2];
  const float* lb   = (const float*)d_in[3];
  const float* W    = (const float*)d_in[4];
  const float* bias = (const float*)d_in[5];
  const int*   inst = (const int*)d_in[6];
  const int*   pad  = (const int*)d_in[7];
  float* out = (float*)d_out;

  char* ws = (char*)d_ws;
  unsigned short* xb  = (unsigned short*)ws;                   // 8388608 B
  unsigned short* Wc  = (unsigned short*)(ws + 8388608);       // 1072*1024*2 = 2195456 B
  unsigned short* B2T = (unsigned short*)(ws + 10584064);      // [1024][32] bf16 = 65536 B
  float* mwzP = (float*)(ws + 10649600);                       // [4][40][4096] f32 = 2621440 B
  unsigned short* gb  = (unsigned short*)(ws + 13271040);      // [4096][32] bf16 = 262144 B
  int*   thr  = (int*)(ws + 13533184);                         // 16 B

  hipLaunchKernelGGL(k_prep,      dim3(4288),   dim3(256),  0, stream,
                     (const float4*)x, (ushort4*)xb, phi, la, Wc);
  hipLaunchKernelGGL(k_mwz,       dim3(4481),   dim3(256),  0, stream,
                     xb, Wc, W, lb, inst, Wc, B2T, thr, mwzP);
  hipLaunchKernelGGL(k_scan_gate, dim3(4, 32),  dim3(1024), 0, stream, mwzP, pad, thr, gb);
  hipLaunchKernelGGL(k_gemm,      dim3(32, 16), dim3(256),  0, stream, xb, Wc, gb, B2T, out, bias);
}